// Round 6
// baseline (77.940 us; speedup 1.0000x reference)
//
#include <hip/hip_runtime.h>
#include <math.h>

// Fused int8-dequant -> causal mask -> softmax -> int8-requant.
// B=4, H=16, S=1024. Input/output int8 materialized as int32 by harness.
// One 64-lane WAVE per row; 4 CONSECUTIVE rows per 256-thread block
// (rows 4b..4b+3: diagonals differ by <=3 cols -> intra-block work is
// near-uniform; inter-block variation smoothed by ~2048 resident blocks
// spanning 8 full S-tiles). Consecutive dispatch order => ONE dense moving
// read window + ONE dense moving write window (fill/copy-like DRAM
// locality). R6 isolates removal of R3's mirror pairing, which created two
// distant address windows per block.
//
// Max-free softmax: |x| <= 128*0.02 = 2.56 -> exp in [0.077,12.7], row sum
// <= 13k, fully fp32-stable (R5 confirmed absmax unchanged).
//
// Loads are issued in straight-line code with per-lane predication BEFORE
// any consumer so 4 loads stay in flight per wave (R4 post-mortem: putting
// load+exp in per-chunk uniform branches serialized loads, -4%).

typedef int int4v __attribute__((ext_vector_type(4)));

__global__ __launch_bounds__(256, 8) void fused_causal_softmax_q(
    const int* __restrict__ xq,          // [B*H*S, S] int32 (int8 values)
    const float* __restrict__ scale_x,   // [H*S]
    const float* __restrict__ scale_out, // [H*S]
    int* __restrict__ out)               // [B*H*S, S] int32 (int8 values)
{
    constexpr int S  = 1024;
    constexpr int HS = 16 * S;

    const int wid  = threadIdx.x >> 6;           // wave id 0..3
    const int lane = threadIdx.x & 63;
    const int row  = (blockIdx.x << 2) + wid;    // consecutive rows
    const int hs   = row & (HS - 1);             // h*S + i (scale index)
    const int i    = hs & (S - 1);               // row within the S x S tile

    const size_t base = (size_t)row * S;
    const int4v* __restrict__ xin = (const int4v*)(xq + base);
    int4v* __restrict__ ov        = (int4v*)(out + base);

    const int liveChunks = (i >> 8) + 1;         // wave-uniform, 1..4

    // ---- 1) zero-stores for dead chunks: dependency-free, issue first ----
    int4v z; z.x = 0; z.y = 0; z.z = 0; z.w = 0;
    #pragma unroll
    for (int k = 0; k < 4; ++k)
        if (k >= liveChunks)
            __builtin_nontemporal_store(z, &ov[(k << 6) + lane]);

    const float sxl = scale_x[hs] * 1.44269504088896341f;  // fold log2(e)
    const float so  = scale_out[hs];

    // ---- 2) issue ALL live loads back-to-back (per-lane predication only) ----
    int4v q[4];
    #pragma unroll
    for (int k = 0; k < 4; ++k) {
        const int j0 = (k << 8) + (lane << 2);
        if (j0 <= i)                             // this int4 has >=1 live elem
            q[k] = __builtin_nontemporal_load(&xin[(k << 6) + lane]);
    }

    // ---- 3) dequant + exp2 + per-lane sum ----
    float e[16];
    float s = 0.0f;
    #pragma unroll
    for (int k = 0; k < 4; ++k) {
        const int j0 = (k << 8) + (lane << 2);
        const int nv = i - j0 + 1;               // valid elems in this int4
        const float e0 = (nv > 0) ? __builtin_amdgcn_exp2f((float)q[k].x * sxl) : 0.0f;
        const float e1 = (nv > 1) ? __builtin_amdgcn_exp2f((float)q[k].y * sxl) : 0.0f;
        const float e2 = (nv > 2) ? __builtin_amdgcn_exp2f((float)q[k].z * sxl) : 0.0f;
        const float e3 = (nv > 3) ? __builtin_amdgcn_exp2f((float)q[k].w * sxl) : 0.0f;
        e[k*4+0] = e0; e[k*4+1] = e1; e[k*4+2] = e2; e[k*4+3] = e3;
        s += (e0 + e1) + (e2 + e3);
    }

    // ---- 4) wave sum reduce (the only cross-lane pass) ----
    #pragma unroll
    for (int off = 32; off > 0; off >>= 1)
        s += __shfl_xor(s, off);

    // out = clip(round(p/so), -128, 127); p >= 0 so only upper clip matters.
    // rintf == round-half-even, matches jnp.round.
    const float kf = 1.0f / (s * so);

    // ---- 5) stores for live chunks ----
    #pragma unroll
    for (int k = 0; k < 4; ++k) {
        if (k < liveChunks) {                    // uniform branch, no consumers
            int4v r;
            r.x = (int)fminf(rintf(e[k*4+0] * kf), 127.0f);
            r.y = (int)fminf(rintf(e[k*4+1] * kf), 127.0f);
            r.z = (int)fminf(rintf(e[k*4+2] * kf), 127.0f);
            r.w = (int)fminf(rintf(e[k*4+3] * kf), 127.0f);
            __builtin_nontemporal_store(r, &ov[(k << 6) + lane]);
        }
    }
}

extern "C" void kernel_launch(void* const* d_in, const int* in_sizes, int n_in,
                              void* d_out, int out_size, void* d_ws, size_t ws_size,
                              hipStream_t stream) {
    const int*   xq = (const int*)d_in[0];
    const float* sx = (const float*)d_in[1];
    const float* so = (const float*)d_in[2];
    int* out = (int*)d_out;

    constexpr int B = 4, H = 16, S = 1024;
    const int rows = B * H * S;                  // 65536 rows
    fused_causal_softmax_q<<<dim3(rows / 4), dim3(256), 0, stream>>>(xq, sx, so, out);
}

// Round 7
// 57.677 us; speedup vs baseline: 1.3513x; 1.3513x over previous
//
#include <hip/hip_runtime.h>
#include <math.h>

// Fused int8-dequant -> causal mask -> softmax -> int8-requant.
// B=4, H=16, S=1024. Input/output int8 materialized as int32 by harness.
// One 64-lane WAVE per row; 4 rows per 256-thread block with MIRROR PAIRING
// (waves 0,1: rows 2b,2b+1; waves 2,3: mirrored rows from the back) so every
// block does exactly ~2 rows of read + 4 rows of write. R6 proved this
// matters (+3.5% over consecutive rows).
//
// Max-free softmax: |x| <= 128*0.02 = 2.56 -> exp in [0.077,12.7], row sum
// <= 13k, fully fp32-stable (R5 confirmed absmax unchanged).
//
// Loads: straight-line, per-lane predicated, issued before any consumer so
// 4 stay in flight per wave (R4 post-mortem). NT on loads (read-once).
// R7 A/B: stores are PLAIN (no nt) -- testing whether NT-store early
// eviction was fragmenting L2->DRAM writeback bursts vs the 6.9 TB/s fills.

typedef int int4v __attribute__((ext_vector_type(4)));

__global__ __launch_bounds__(256, 8) void fused_causal_softmax_q(
    const int* __restrict__ xq,          // [B*H*S, S] int32 (int8 values)
    const float* __restrict__ scale_x,   // [H*S]
    const float* __restrict__ scale_out, // [H*S]
    int* __restrict__ out)               // [B*H*S, S] int32 (int8 values)
{
    constexpr int S    = 1024;
    constexpr int HS   = 16 * S;
    constexpr int ROWS = 4 * HS;                 // 65536

    const int wid  = threadIdx.x >> 6;           // wave id 0..3
    const int lane = threadIdx.x & 63;
    const int fr   = (blockIdx.x << 1) + (wid & 1);
    const int row  = (wid < 2) ? fr : (ROWS - 1 - fr);   // mirror pairing
    const int hs   = row & (HS - 1);             // h*S + i (scale index)
    const int i    = hs & (S - 1);               // row within the S x S tile

    const size_t base = (size_t)row * S;
    const int4v* __restrict__ xin = (const int4v*)(xq + base);
    int4v* __restrict__ ov        = (int4v*)(out + base);

    const int liveChunks = (i >> 8) + 1;         // wave-uniform, 1..4

    // ---- 1) zero-stores for dead chunks: dependency-free, issue first ----
    int4v z; z.x = 0; z.y = 0; z.z = 0; z.w = 0;
    #pragma unroll
    for (int k = 0; k < 4; ++k)
        if (k >= liveChunks)
            ov[(k << 6) + lane] = z;

    const float sxl = scale_x[hs] * 1.44269504088896341f;  // fold log2(e)
    const float so  = scale_out[hs];

    // ---- 2) issue ALL live loads back-to-back (per-lane predication only) ----
    int4v q[4];
    #pragma unroll
    for (int k = 0; k < 4; ++k) {
        const int j0 = (k << 8) + (lane << 2);
        if (j0 <= i)                             // this int4 has >=1 live elem
            q[k] = __builtin_nontemporal_load(&xin[(k << 6) + lane]);
    }

    // ---- 3) dequant + exp2 + per-lane sum ----
    float e[16];
    float s = 0.0f;
    #pragma unroll
    for (int k = 0; k < 4; ++k) {
        const int j0 = (k << 8) + (lane << 2);
        const int nv = i - j0 + 1;               // valid elems in this int4
        const float e0 = (nv > 0) ? __builtin_amdgcn_exp2f((float)q[k].x * sxl) : 0.0f;
        const float e1 = (nv > 1) ? __builtin_amdgcn_exp2f((float)q[k].y * sxl) : 0.0f;
        const float e2 = (nv > 2) ? __builtin_amdgcn_exp2f((float)q[k].z * sxl) : 0.0f;
        const float e3 = (nv > 3) ? __builtin_amdgcn_exp2f((float)q[k].w * sxl) : 0.0f;
        e[k*4+0] = e0; e[k*4+1] = e1; e[k*4+2] = e2; e[k*4+3] = e3;
        s += (e0 + e1) + (e2 + e3);
    }

    // ---- 4) wave sum reduce (the only cross-lane pass) ----
    #pragma unroll
    for (int off = 32; off > 0; off >>= 1)
        s += __shfl_xor(s, off);

    // out = clip(round(p/so), -128, 127); p >= 0 so only upper clip matters.
    // rintf == round-half-even, matches jnp.round.
    const float kf = 1.0f / (s * so);

    // ---- 5) stores for live chunks ----
    #pragma unroll
    for (int k = 0; k < 4; ++k) {
        if (k < liveChunks) {                    // uniform branch, no consumers
            int4v r;
            r.x = (int)fminf(rintf(e[k*4+0] * kf), 127.0f);
            r.y = (int)fminf(rintf(e[k*4+1] * kf), 127.0f);
            r.z = (int)fminf(rintf(e[k*4+2] * kf), 127.0f);
            r.w = (int)fminf(rintf(e[k*4+3] * kf), 127.0f);
            ov[(k << 6) + lane] = r;
        }
    }
}

extern "C" void kernel_launch(void* const* d_in, const int* in_sizes, int n_in,
                              void* d_out, int out_size, void* d_ws, size_t ws_size,
                              hipStream_t stream) {
    const int*   xq = (const int*)d_in[0];
    const float* sx = (const float*)d_in[1];
    const float* so = (const float*)d_in[2];
    int* out = (int*)d_out;

    constexpr int B = 4, H = 16, S = 1024;
    const int rows = B * H * S;                  // 65536 rows
    // each block covers 2 front rows + 2 mirrored back rows
    fused_causal_softmax_q<<<dim3(rows / 4), dim3(256), 0, stream>>>(xq, sx, so, out);
}